// Round 9
// baseline (2664.957 us; speedup 1.0000x reference)
//
#include <hip/hip_runtime.h>
#include <hip/hip_bf16.h>
#include <initializer_list>

typedef _Float16 half8 __attribute__((ext_vector_type(8)));
typedef float floatx4 __attribute__((ext_vector_type(4)));

#define MFMA16(a, b, c) __builtin_amdgcn_mfma_f32_16x16x32_f16((a), (b), (c), 0, 0, 0)

// ---------------------------------------------------------------- LayerNorm
// one block (256 threads) per row of 512; fp32 in, fp32 math, fp16 out
__global__ __launch_bounds__(256) void ln_kernel(const float* __restrict__ x,
                                                 const float* __restrict__ gamma,
                                                 const float* __restrict__ beta,
                                                 _Float16* __restrict__ xn) {
    int row = blockIdx.x;
    int tid = threadIdx.x;
    float2 v = ((const float2*)(x + (size_t)row * 512))[tid];

    __shared__ float red[4];
    __shared__ float mv[2];

    float s = v.x + v.y;
#pragma unroll
    for (int o = 32; o > 0; o >>= 1) s += __shfl_down(s, o);
    if ((tid & 63) == 0) red[tid >> 6] = s;
    __syncthreads();
    if (tid == 0) mv[0] = (red[0] + red[1] + red[2] + red[3]) * (1.f / 512.f);
    __syncthreads();
    float mean = mv[0];

    float dx = v.x - mean, dy = v.y - mean;
    float sq = dx * dx + dy * dy;
#pragma unroll
    for (int o = 32; o > 0; o >>= 1) sq += __shfl_xor(sq, o);
    __syncthreads();
    if ((tid & 63) == 0) red[tid >> 6] = sq;
    __syncthreads();
    if (tid == 0) mv[1] = rsqrtf((red[0] + red[1] + red[2] + red[3]) * (1.f / 512.f) + 1e-5f);
    __syncthreads();
    float rstd = mv[1];

    float g0 = gamma[tid * 2], g1 = gamma[tid * 2 + 1];
    float b0 = beta[tid * 2], b1 = beta[tid * 2 + 1];
    union { _Float16 h[2]; unsigned int u; } pk;
    pk.h[0] = (_Float16)(dx * rstd * g0 + b0);
    pk.h[1] = (_Float16)(dy * rstd * g1 + b1);
    ((unsigned int*)(xn + (size_t)row * 512))[tid] = pk.u;
}

// ------------------------------------------------- transpose + cast fp32->fp16
__global__ void transpose_cast(const float* __restrict__ in, _Float16* __restrict__ out,
                               int R, int C) {
    int idx = blockIdx.x * 256 + threadIdx.x;
    if (idx >= R * C) return;
    int orow = idx / R;
    int ocol = idx - orow * R;
    out[idx] = (_Float16)in[(size_t)ocol * C + orow];
}

// ---------------------------------------------------------------- GEMM (B^T)
// C[M,N] = A[M,K] @ Bt[N,K]^T + bias[N]
// OUTMODE: 0 -> fp16 store (intermediate), 1 -> fp32 store (final output)
template <int OUTMODE>
__global__ __launch_bounds__(256) void gemm_bt(const _Float16* __restrict__ A,
                                               const _Float16* __restrict__ Bt,
                                               const float* __restrict__ bias,
                                               void* __restrict__ Cout,
                                               int M, int N, int K) {
    __shared__ __align__(16) _Float16 Asb[128 * 40];
    __shared__ __align__(16) _Float16 Bsb[128 * 40];

    int m0 = blockIdx.x * 128;
    int n0 = blockIdx.y * 128;
    int tid = threadIdx.x;
    int w = tid >> 6, lane = tid & 63, lrow = lane & 15, quad = lane >> 4;
    int wm = (w >> 1) * 64, wn = (w & 1) * 64;

    floatx4 acc[4][4];
#pragma unroll
    for (int i = 0; i < 4; ++i)
#pragma unroll
        for (int j = 0; j < 4; ++j) acc[i][j] = (floatx4){0.f, 0.f, 0.f, 0.f};

    for (int k0 = 0; k0 < K; k0 += 32) {
        __syncthreads();
#pragma unroll
        for (int it = 0; it < 2; ++it) {
            int c = tid + it * 256;
            int rr = c >> 2;
            int c8 = (c & 3) * 8;
            uint4 ta = *(const uint4*)(A + (size_t)(m0 + rr) * K + k0 + c8);
            uint4 tb = *(const uint4*)(Bt + (size_t)(n0 + rr) * K + k0 + c8);
            *(uint4*)&Asb[rr * 40 + c8] = ta;
            *(uint4*)&Bsb[rr * 40 + c8] = tb;
        }
        __syncthreads();

        half8 af[4], bf[4];
#pragma unroll
        for (int i = 0; i < 4; ++i)
            af[i] = *(const half8*)&Asb[(wm + i * 16 + lrow) * 40 + quad * 8];
#pragma unroll
        for (int j = 0; j < 4; ++j)
            bf[j] = *(const half8*)&Bsb[(wn + j * 16 + lrow) * 40 + quad * 8];
#pragma unroll
        for (int i = 0; i < 4; ++i)
#pragma unroll
            for (int j = 0; j < 4; ++j)
                acc[i][j] = MFMA16(af[i], bf[j], acc[i][j]);
    }

#pragma unroll
    for (int i = 0; i < 4; ++i)
#pragma unroll
        for (int j = 0; j < 4; ++j) {
            int colg = n0 + wn + j * 16 + lrow;
            float bv = bias[colg];
#pragma unroll
            for (int r = 0; r < 4; ++r) {
                int rowg = m0 + wm + i * 16 + quad * 4 + r;
                float v = acc[i][j][r] + bv;
                if (OUTMODE == 1)
                    ((float*)Cout)[(size_t)rowg * N + colg] = v;   // fp32 final output
                else
                    ((_Float16*)Cout)[(size_t)rowg * N + colg] = (_Float16)v;
            }
        }
}

// ---------------------------------------------------------------- attention
// qkv layout per (b,n): H blocks of 384 = [q 64][k 64][v 256], fp16
// grid (16 qtiles, 8 heads, CB batch), 256 threads; wave w owns queries qt*64+w*16..+15
__global__ __launch_bounds__(256) void attn_kernel(const _Float16* __restrict__ qkv,
                                                   const float* __restrict__ biases,
                                                   _Float16* __restrict__ out) {
    int qt = blockIdx.x, h = blockIdx.y, b = blockIdx.z;
    int tid = threadIdx.x;
    int w = tid >> 6, lane = tid & 63, lrow = lane & 15, quad = lane >> 4;

    __shared__ float bias_lds[1024];
    __shared__ __align__(16) _Float16 K_lds[32 * 72];      // [key][kd] stride 72
    __shared__ __align__(16) _Float16 V_t[256 * 40];       // [d][key] stride 40
    __shared__ __align__(16) _Float16 P_lds[4 * 16 * 40];  // per-wave [q][key] stride 40

    for (int i = tid; i < 1024; i += 256) bias_lds[i] = biases[h * 1024 + i];

    const size_t base_bn = (size_t)b * 1024 * 3072;

    int qrow = qt * 64 + w * 16 + lrow;
    half8 aq[2];
#pragma unroll
    for (int c = 0; c < 2; ++c)
        aq[c] = *(const half8*)(qkv + base_bn + (size_t)qrow * 3072 + h * 384 + c * 32 + quad * 8);

    float m_r[4], l_r[4];
#pragma unroll
    for (int r = 0; r < 4; ++r) { m_r[r] = -1e30f; l_r[r] = 0.f; }
    floatx4 od[16];
#pragma unroll
    for (int dt = 0; dt < 16; ++dt) od[dt] = (floatx4){0.f, 0.f, 0.f, 0.f};

    int qg[4], qr2[4], qc2[4];
#pragma unroll
    for (int r = 0; r < 4; ++r) {
        qg[r] = qt * 64 + w * 16 + quad * 4 + r;
        qr2[r] = qg[r] >> 5;
        qc2[r] = qg[r] & 31;
    }

    _Float16* Pw = &P_lds[w * 640];

    for (int kt = 0; kt < 32; ++kt) {
        __syncthreads();
        {
            int key_l = tid >> 3;
            int d8 = (tid & 7) * 8;
            uint4 t = *(const uint4*)(qkv + base_bn + (size_t)(kt * 32 + key_l) * 3072 + h * 384 + 64 + d8);
            *(uint4*)&K_lds[key_l * 72 + d8] = t;
        }
#pragma unroll
        for (int it = 0; it < 4; ++it) {
            int c = tid + it * 256;
            int key_l = c >> 5;
            int d8 = (c & 31) * 8;
            half8 t = *(const half8*)(qkv + base_bn + (size_t)(kt * 32 + key_l) * 3072 + h * 384 + 128 + d8);
#pragma unroll
            for (int jj = 0; jj < 8; ++jj) V_t[(d8 + jj) * 40 + key_l] = t[jj];
        }
        __syncthreads();

        floatx4 sc[2];
#pragma unroll
        for (int t = 0; t < 2; ++t) {
            sc[t] = (floatx4){0.f, 0.f, 0.f, 0.f};
            half8 bk0 = *(const half8*)&K_lds[(t * 16 + lrow) * 72 + quad * 8];
            half8 bk1 = *(const half8*)&K_lds[(t * 16 + lrow) * 72 + 32 + quad * 8];
            sc[t] = MFMA16(aq[0], bk0, sc[t]);
            sc[t] = MFMA16(aq[1], bk1, sc[t]);
        }
        float sv[2][4];
#pragma unroll
        for (int t = 0; t < 2; ++t) {
            int kg = kt * 32 + t * 16 + lrow;
            int kr = kg >> 5, kc = kg & 31;
#pragma unroll
            for (int r = 0; r < 4; ++r) {
                int idx = abs(qr2[r] - kr) * 32 + abs(qc2[r] - kc);
                sv[t][r] = sc[t][r] * 0.125f + bias_lds[idx];
            }
        }
        float alpha[4];
#pragma unroll
        for (int r = 0; r < 4; ++r) {
            float mx = fmaxf(sv[0][r], sv[1][r]);
#pragma unroll
            for (int o = 1; o < 16; o <<= 1) mx = fmaxf(mx, __shfl_xor(mx, o));
            float nm = fmaxf(m_r[r], mx);
            alpha[r] = __expf(m_r[r] - nm);
            m_r[r] = nm;
            float p0 = __expf(sv[0][r] - nm);
            float p1 = __expf(sv[1][r] - nm);
            sv[0][r] = p0; sv[1][r] = p1;
            float rs = p0 + p1;
#pragma unroll
            for (int o = 1; o < 16; o <<= 1) rs += __shfl_xor(rs, o);
            l_r[r] = l_r[r] * alpha[r] + rs;
        }
#pragma unroll
        for (int dt = 0; dt < 16; ++dt)
#pragma unroll
            for (int r = 0; r < 4; ++r) od[dt][r] *= alpha[r];
#pragma unroll
        for (int t = 0; t < 2; ++t)
#pragma unroll
            for (int r = 0; r < 4; ++r)
                Pw[(quad * 4 + r) * 40 + t * 16 + lrow] = (_Float16)sv[t][r];
        __syncthreads();

        half8 ap = *(const half8*)&Pw[lrow * 40 + quad * 8];
#pragma unroll
        for (int dt = 0; dt < 16; ++dt) {
            half8 bv = *(const half8*)&V_t[(dt * 16 + lrow) * 40 + quad * 8];
            od[dt] = MFMA16(ap, bv, od[dt]);
        }
    }

#pragma unroll
    for (int dt = 0; dt < 16; ++dt)
#pragma unroll
        for (int r = 0; r < 4; ++r) {
            float v = od[dt][r] / l_r[r];
            out[((size_t)b * 1024 + qg[r]) * 2048 + h * 256 + dt * 16 + lrow] = (_Float16)v;
        }
}

// ---------------------------------------------------------------- launch
extern "C" void kernel_launch(void* const* d_in, const int* in_sizes, int n_in,
                              void* d_out, int out_size, void* d_ws, size_t ws_size,
                              hipStream_t stream) {
    // Inputs fp32 (verified: round-5 on-device detector + round-4 NaN forensics).
    const float* x      = (const float*)d_in[0];
    const float* gamma  = (const float*)d_in[1];
    const float* beta   = (const float*)d_in[2];
    const float* qkv_w  = (const float*)d_in[3];
    const float* qkv_b  = (const float*)d_in[4];
    const float* proj_w = (const float*)d_in[5];
    const float* proj_b = (const float*)d_in[6];
    const float* biases = (const float*)d_in[7];
    // d_in[8] = bias_idxs: computed analytically in-kernel

    // OUTPUT IS FP32: reference returns float32; harness reads float32.
    // (Rounds 2-8 wrote bf16 -> packed-pair misread -> the constant 0.0928.)
    float* out = (float*)d_out;

    _Float16* ws      = (_Float16*)d_ws;
    _Float16* qkv_wt  = ws;                                   //  512*3072
    _Float16* proj_wt = qkv_wt + (size_t)512 * 3072;          // 2048*512
    _Float16* xn      = proj_wt + (size_t)2048 * 512;         // 32768*512
    _Float16* chunk0  = xn + (size_t)32768 * 512;

    const size_t FIXED_HALVES = (size_t)512 * 3072 + (size_t)2048 * 512 + (size_t)32768 * 512;
    int CB = 0;
    for (int cb : {16, 8, 4, 2, 1}) {
        size_t halves = FIXED_HALVES + (size_t)cb * 1024 * (3072 + 2048);
        if (halves * sizeof(_Float16) <= ws_size) { CB = cb; break; }
    }
    if (CB == 0) return;
    _Float16* qkv_c = chunk0;                                 // CB*1024*3072
    _Float16* att_c = qkv_c + (size_t)CB * 1024 * 3072;       // CB*1024*2048

    transpose_cast<<<(512 * 3072 + 255) / 256, 256, 0, stream>>>(qkv_w, qkv_wt, 512, 3072);
    transpose_cast<<<(2048 * 512 + 255) / 256, 256, 0, stream>>>(proj_w, proj_wt, 2048, 512);
    ln_kernel<<<32768, 256, 0, stream>>>(x, gamma, beta, xn);

    const int MC = CB * 1024;
    for (int c = 0; c < 32 / CB; ++c) {
        const _Float16* xn_c = xn + (size_t)c * MC * 512;
        gemm_bt<0><<<dim3(MC / 128, 24), 256, 0, stream>>>(xn_c, qkv_wt, qkv_b,
                                                           (void*)qkv_c, MC, 3072, 512);
        attn_kernel<<<dim3(16, 8, CB), 256, 0, stream>>>(qkv_c, biases, att_c);
        float* out_c = out + (size_t)c * MC * 512;
        gemm_bt<1><<<dim3(MC / 128, 4), 256, 0, stream>>>(att_c, proj_wt, proj_b,
                                                          (void*)out_c, MC, 512, 2048);
    }
}